// Round 2
// baseline (116.358 us; speedup 1.0000x reference)
//
#include <hip/hip_runtime.h>

#define HH 256
#define WW 256
#define HW (HH * WW)
#define NB 8
#define NPTS 65536
#define EPSW 1e-5f
#define BIGBITS 0x501502F9u       // __float_as_uint(1e10f)

#define TPB 64                    // 32x32 tiles per image (8x8)
#define SDS 36                    // accumulator stride: (36r+c)%32 -> <=2-way on 8x8 = free
#define VCAP 384                  // compacted visible list cap (mean ~92)
#define SCAP 2048                 // staged +-3-window points cap (mean ~1444, +16 sigma)
#define ZRW 42                    // z-image cols: [base_j-5, base_j+36]
#define ZRH 42
#define ZMW 38                    // zmin cols: [base_j-3, base_j+34]
#define ZMH 38

// ---- ONE kernel: per 32x32 tile, scan the image's points directly ----
// Routing-by-broadcast: all 64 blocks of image b stream the same 768 KB pts
// slice (L2-resident on one XCD via blockIdx&7 mapping). Removes bin kernel,
// entries round-trip, counts, memset, and all binning overflow risk.
__global__ void __launch_bounds__(1024, 8) render_k(
        const float* __restrict__ pts, const float* __restrict__ thr_p,
        float* __restrict__ vis, float* __restrict__ depth, float* __restrict__ weight) {
    __shared__ unsigned int zraw[ZRH * ZRW];   // 7.1 KB own-pixel min (uint bits)
    __shared__ float hmin[ZRH * ZMW];          // 6.4 KB
    __shared__ float zminb[ZMH * ZMW];         // 5.8 KB
    __shared__ float sdep[32 * SDS];           // 4.6 KB
    __shared__ float swei[32 * SDS];           // 4.6 KB
    __shared__ float vx[VCAP], vy[VCAP], vz[VCAP];  // 4.6 KB
    __shared__ float4 staged[SCAP];            // 32 KB -> total ~65.8 KB, 2 blocks/CU
    __shared__ int scnt, vcnt;

    int b  = blockIdx.x & 7;                   // image -> XCD (i%8 round-robin): pts L2-resident
    int tr = blockIdx.x >> 3;                  // tile 0..63
    int ty = tr >> 3, tx = tr & 7;
    int base_i = ty * 32, base_j = tx * 32;
    int tid = threadIdx.x;
    float thr = *thr_p;

    if (tid == 0) { scnt = 0; vcnt = 0; }
    // P1: init z-image + accumulators
    for (int t = tid; t < ZRH * ZRW; t += 1024) zraw[t] = BIGBITS;
    for (int t = tid; t < 32 * SDS; t += 1024) { sdep[t] = 0.0f; swei[t] = 0.0f; }
    __syncthreads();   // S1

    // P2: scan all points of image b; +-5 window -> zraw min; +-3 window -> stage
    const float* P = pts + (size_t)b * NPTS * 3;
    for (int g = tid; g < NPTS; g += 1024) {
        float x = P[g * 3 + 0];
        float y = P[g * 3 + 1];
        float z = P[g * 3 + 2];
        int px = __float2int_rn(x);            // round-half-even = jnp.round
        int py = __float2int_rn(y);
        int r5 = py - base_i + 5, c5 = px - base_j + 5;
        if ((unsigned)r5 < (unsigned)ZRH && (unsigned)c5 < (unsigned)ZRW) {
            atomicMin(&zraw[r5 * ZRW + c5], __float_as_uint(z));  // uint==float order (z>0)
            if ((unsigned)(r5 - 2) < (unsigned)ZMH && (unsigned)(c5 - 2) < (unsigned)ZMW) {
                int s = atomicAdd(&scnt, 1);
                if (s < SCAP)
                    staged[s] = make_float4(x, y, z, __uint_as_float((unsigned)(b * NPTS + g)));
            }
        }
    }
    __syncthreads();   // S2

    // P3: horizontal 5-min
    for (int t = tid; t < ZRH * ZMW; t += 1024) {
        int r = t / ZMW, c = t - r * ZMW;
        const unsigned int* p = &zraw[r * ZRW + c];
        float m = fminf(__uint_as_float(p[0]), __uint_as_float(p[1]));
        m = fminf(m, fminf(__uint_as_float(p[2]), __uint_as_float(p[3])));
        hmin[t] = fminf(m, __uint_as_float(p[4]));
    }
    __syncthreads();   // S3

    // P4: vertical 5-min
    for (int t = tid; t < ZMH * ZMW; t += 1024) {
        int c = t % ZMW;
        const float* p = &hmin[(t / ZMW) * ZMW + c];
        zminb[t] = fminf(fminf(fminf(p[0], p[ZMW]), fminf(p[2 * ZMW], p[3 * ZMW])), p[4 * ZMW]);
    }
    __syncthreads();   // S4

    // P5: visibility, vis write (home tile), compact visible list
    int n = scnt; if (n > SCAP) n = SCAP;
    for (int g = tid; g < n; g += 1024) {
        float4 p = staged[g];
        int px = __float2int_rn(p.x);
        int py = __float2int_rn(p.y);
        float zmin = zminb[(py - base_i + 3) * ZMW + (px - base_j + 3)];
        bool visible = (p.z <= zmin + thr);
        if (((px >> 5) == tx) && ((py >> 5) == ty))   // home tile writes vis once
            vis[__float_as_uint(p.w)] = visible ? 1.0f : 0.0f;
        if (visible) {
            int vp = atomicAdd(&vcnt, 1);
            if (vp < VCAP) { vx[vp] = p.x; vy[vp] = p.y; vz[vp] = p.z; }
        }
    }
    __syncthreads();   // S5

    // P6: tap-parallel splat; (e,tap) tracked incrementally (step +1024 = +20e +44t)
    int nv = vcnt; if (nv > VCAP) nv = VCAP;
    int total3 = nv * 49;
    int e = (int)((unsigned int)tid / 49u);            // one-time exact division
    int tap = tid - e * 49;
    for (int g = tid; g < total3; g += 1024) {
        int r = ((unsigned int)(tap * 37)) >> 8;       // tap/7, exact for 0..48
        int c = tap - r * 7;
        float x = vx[e], y = vy[e], z = vz[e];
        int px = __float2int_rn(x);
        int py = __float2int_rn(y);
        int ii = py - 3 + r, jj = px - 3 + c;
        int li = ii - base_i, lj = jj - base_j;
        if (li >= 0 && li < 32 && lj >= 0 && lj < 32) {
            float dy = y - (float)ii, dx = x - (float)jj;
            float w = 1.0f / (dx * dx + dy * dy + EPSW);
            atomicAdd(&sdep[li * SDS + lj], w * z);
            atomicAdd(&swei[li * SDS + lj], w);
        }
        e += 20; tap += 44;                            // 1024 = 20*49 + 44
        if (tap >= 49) { tap -= 49; e += 1; }
    }
    __syncthreads();   // S6

    // P7: dense coalesced stores (each pixel owned by exactly one tile)
    for (int t = tid; t < 32 * 32; t += 1024) {
        int li = t >> 5, lj = t & 31;
        int g = b * HW + (base_i + li) * WW + (base_j + lj);
        depth[g]  = sdep[li * SDS + lj];
        weight[g] = swei[li * SDS + lj];
    }
}

extern "C" void kernel_launch(void* const* d_in, const int* in_sizes, int n_in,
                              void* d_out, int out_size, void* d_ws, size_t ws_size,
                              hipStream_t stream) {
    const float* pts   = (const float*)d_in[0];   // [B, N, 3]
    const float* thr_p = (const float*)d_in[1];   // scalar

    float* depth  = (float*)d_out;                 // [B*H*W]
    float* weight = depth + NB * HW;               // [B*H*W]
    float* vis    = weight + NB * HW;              // [B*N]

    (void)d_ws; (void)ws_size;                     // no workspace needed
    render_k<<<NB * TPB, 1024, 0, stream>>>(pts, thr_p, vis, depth, weight);
}